// Round 14
// baseline (182.621 us; speedup 1.0000x reference)
//
#include <hip/hip_runtime.h>
#include <hip/hip_bf16.h>

#define NN 100000
#define NE 1600000
#define DIM 128
#define BM 64
#define CAP 28
#define OVFCAP 2048        // per slice
#define CVT_BLK 1024
#define SC_BLK 2048
#define SLICE 12544        // 196*64 nodes per XCD slice
#define FGRID 1568         // 8*196

typedef __attribute__((ext_vector_type(8))) short short8;
typedef __attribute__((ext_vector_type(4))) float f32x4;
typedef __attribute__((ext_vector_type(4))) unsigned short ushort4v;
typedef __attribute__((ext_vector_type(4))) int int4v;

__device__ __forceinline__ unsigned short f2bf(float f) {
  union { float f; unsigned u; } v; v.f = f;
  unsigned r = v.u + 0x7fffu + ((v.u >> 16) & 1u);
  return (unsigned short)(r >> 16);
}
__device__ __forceinline__ float bf2f(unsigned short h) {
  union { unsigned u; float f; } v; v.u = ((unsigned)h) << 16;
  return v.f;
}

// K1: XCD-sliced prep. cvt block b: x-slice b&7 -> bf16. scatter block:
// only dst in slice sb&7 (slot/cnt/ovf lines single-XCD); dst scanned via
// int4 loads (4 edges/load).
__global__ __launch_bounds__(256) void prep_scatter_kernel(
    const float* __restrict__ x, const int* __restrict__ ei,
    const float* __restrict__ Wn, const float* __restrict__ bn,
    const float* __restrict__ Ws, const float* __restrict__ bs,
    unsigned short* __restrict__ xb, unsigned short* __restrict__ wnb,
    unsigned short* __restrict__ wsb, float* __restrict__ bsum,
    int* __restrict__ cnt, int* __restrict__ ovfcnt, int2* __restrict__ ovf,
    int* __restrict__ slots) {
  int b = blockIdx.x;
  if (b < CVT_BLK) {
    const int slice = b & 7;
    const int tid_g = (b >> 3) * 256 + threadIdx.x;
    const int r0 = slice * SLICE;
    const int r1 = min(r0 + SLICE, NN);
    const int i0 = r0 * (DIM / 4), i1 = r1 * (DIM / 4);
    for (int i = i0 + tid_g; i < i1; i += 128 * 256) {
      f32x4 v = reinterpret_cast<const f32x4*>(x)[i];
      ushort4v u;
      u[0] = f2bf(v[0]); u[1] = f2bf(v[1]); u[2] = f2bf(v[2]); u[3] = f2bf(v[3]);
      reinterpret_cast<ushort4v*>(xb)[i] = u;
    }
    if (slice == 0) {
      if (tid_g < DIM * DIM) { wnb[tid_g] = f2bf(Wn[tid_g]); wsb[tid_g] = f2bf(Ws[tid_g]); }
      if (tid_g < DIM) bsum[tid_g] = bn[tid_g] + bs[tid_g];
    }
  } else {
    const int sb  = b - CVT_BLK;              // 0..2047
    const int sl  = sb & 7;
    const int lo  = sl * SLICE;
    const int hi  = min(lo + SLICE, NN);
    const int rng = hi - lo;
    const int tid_g = (sb >> 3) * 256 + threadIdx.x;  // 0..65535
    const int STR = 256 * 256;                // threads per slice group
    const int NCH = NE / 4;                   // 400000 4-edge chunks
    for (int c = tid_g; c < NCH; c += STR) {
      int4v d4 = *reinterpret_cast<const int4v*>(ei + NE + 4 * c);
      #pragma unroll
      for (int j = 0; j < 4; ++j) {
        int d = d4[j];
        if ((unsigned)(d - lo) < (unsigned)rng) {
          int s = ei[4 * c + j];
          if ((unsigned)s >= NN) continue;
          int r = atomicAdd(&cnt[d], 1);
          if (r < CAP) {
            slots[d * CAP + r] = s;
          } else {
            int o = atomicAdd(&ovfcnt[sl], 1);
            if (o < OVFCAP) ovf[sl * OVFCAP + o] = make_int2(d, s);
          }
        }
      }
    }
  }
}

// K2: fused aggregate + dual MFMA GEMM. No sX: LDS 34KB -> 4 blocks/CU
// (32 waves) for gather latency hiding. Self-row A-fragments preloaded to
// regs from L2-local xb (same XCD slice), reused across both Ws stages.
__global__ __launch_bounds__(512) void fusedgemm_kernel(
    const unsigned short* __restrict__ xb,
    const int* __restrict__ cnt, const int* __restrict__ slots,
    const int2* __restrict__ ovf, const int* __restrict__ ovfcnt,
    const unsigned short* __restrict__ wnb, const unsigned short* __restrict__ wsb,
    const float* __restrict__ bsum, float* __restrict__ out) {
  __shared__ unsigned short sW[64 * DIM];   // 16KB (one 64-row half of W)
  __shared__ unsigned short sA[BM * DIM];   // 16KB
  __shared__ int2 lovf[256];                // 2KB
  __shared__ int lovfn;
  const int tid = threadIdx.x;
  const int slice = blockIdx.x & 7;
  const int row0 = slice * SLICE + (blockIdx.x >> 3) * BM;
  if (row0 >= NN) return;

  if (tid == 0) lovfn = 0;
  // stage sW = Wn rows 0-63
  {
    int id = tid;
    #pragma unroll
    for (int it = 0; it < 2; ++it, id += 512) {
      int r = id >> 4, c = id & 15;
      short8 w = *reinterpret_cast<const short8*>(wnb + r * DIM + c * 8);
      int off = (r * 256 + c * 16) ^ ((r & 7) << 4);
      *reinterpret_cast<short8*>(reinterpret_cast<char*>(sW) + off) = w;
    }
  }
  __syncthreads();   // lovfn init visible

  // pick this block's overflow pairs from ITS SLICE's list only
  {
    int ovfn = min(ovfcnt[slice], OVFCAP);
    const int2* osl = ovf + slice * OVFCAP;
    for (int k = tid; k < ovfn; k += 512) {
      int2 p = osl[k];
      if ((unsigned)(p.x - row0) < (unsigned)BM) {
        int t = atomicAdd(&lovfn, 1);
        if (t < 256) lovf[t] = p;
      }
    }
  }
  __syncthreads();

  // aggregate: 16 groups x 32 lanes; 4 nodes per group; idx prefetch 1 ahead
  {
    const int lg = tid >> 5, ln = tid & 31;
    int g = row0 + lg;
    int m = 0, idx = 0;
    if (g < NN) {
      m = min(cnt[g], CAP);
      if (ln < m) idx = slots[g * CAP + ln];
    }
    const int lcnt = min(lovfn, 256);
    for (int it = 0; it < 4; ++it) {
      int r = it * 16 + lg;
      int gcur = row0 + r;
      int mn = 0, idxn = 0;
      if (it < 3) {
        int gn = row0 + (it + 1) * 16 + lg;
        if (gn < NN) {
          mn = min(cnt[gn], CAP);
          if (ln < mn) idxn = slots[gn * CAP + ln];
        }
      }
      f32x4 a0 = (f32x4){0.f,0.f,0.f,0.f}, a1 = a0, a2 = a0, a3 = a0;
      f32x4 a4 = a0, a5 = a0, a6 = a0, a7 = a0;
      int e = 0;
      for (; e + 7 < m; e += 8) {
        int s0 = __shfl(idx, e, 32),     s1 = __shfl(idx, e + 1, 32);
        int s2 = __shfl(idx, e + 2, 32), s3 = __shfl(idx, e + 3, 32);
        int s4 = __shfl(idx, e + 4, 32), s5 = __shfl(idx, e + 5, 32);
        int s6 = __shfl(idx, e + 6, 32), s7 = __shfl(idx, e + 7, 32);
        ushort4v u0 = *reinterpret_cast<const ushort4v*>(xb + (size_t)s0 * DIM + ln * 4);
        ushort4v u1 = *reinterpret_cast<const ushort4v*>(xb + (size_t)s1 * DIM + ln * 4);
        ushort4v u2 = *reinterpret_cast<const ushort4v*>(xb + (size_t)s2 * DIM + ln * 4);
        ushort4v u3 = *reinterpret_cast<const ushort4v*>(xb + (size_t)s3 * DIM + ln * 4);
        ushort4v u4 = *reinterpret_cast<const ushort4v*>(xb + (size_t)s4 * DIM + ln * 4);
        ushort4v u5 = *reinterpret_cast<const ushort4v*>(xb + (size_t)s5 * DIM + ln * 4);
        ushort4v u6 = *reinterpret_cast<const ushort4v*>(xb + (size_t)s6 * DIM + ln * 4);
        ushort4v u7 = *reinterpret_cast<const ushort4v*>(xb + (size_t)s7 * DIM + ln * 4);
        #pragma unroll
        for (int j = 0; j < 4; ++j) {
          a0[j] += bf2f(u0[j]); a1[j] += bf2f(u1[j]);
          a2[j] += bf2f(u2[j]); a3[j] += bf2f(u3[j]);
          a4[j] += bf2f(u4[j]); a5[j] += bf2f(u5[j]);
          a6[j] += bf2f(u6[j]); a7[j] += bf2f(u7[j]);
        }
      }
      for (; e + 3 < m; e += 4) {
        int s0 = __shfl(idx, e, 32),     s1 = __shfl(idx, e + 1, 32);
        int s2 = __shfl(idx, e + 2, 32), s3 = __shfl(idx, e + 3, 32);
        ushort4v u0 = *reinterpret_cast<const ushort4v*>(xb + (size_t)s0 * DIM + ln * 4);
        ushort4v u1 = *reinterpret_cast<const ushort4v*>(xb + (size_t)s1 * DIM + ln * 4);
        ushort4v u2 = *reinterpret_cast<const ushort4v*>(xb + (size_t)s2 * DIM + ln * 4);
        ushort4v u3 = *reinterpret_cast<const ushort4v*>(xb + (size_t)s3 * DIM + ln * 4);
        #pragma unroll
        for (int j = 0; j < 4; ++j) {
          a0[j] += bf2f(u0[j]); a1[j] += bf2f(u1[j]);
          a2[j] += bf2f(u2[j]); a3[j] += bf2f(u3[j]);
        }
      }
      for (; e < m; ++e) {
        int s0 = __shfl(idx, e, 32);
        ushort4v u0 = *reinterpret_cast<const ushort4v*>(xb + (size_t)s0 * DIM + ln * 4);
        #pragma unroll
        for (int j = 0; j < 4; ++j) a0[j] += bf2f(u0[j]);
      }
      for (int k2 = 0; k2 < lcnt; ++k2) {
        int2 p = lovf[k2];
        if (p.x == gcur) {
          ushort4v u0 = *reinterpret_cast<const ushort4v*>(xb + (size_t)p.y * DIM + ln * 4);
          #pragma unroll
          for (int j = 0; j < 4; ++j) a0[j] += bf2f(u0[j]);
        }
      }
      a0 += a1; a2 += a3; a4 += a5; a6 += a7;
      a0 += a2; a4 += a6; a0 += a4;
      ushort4v o;
      o[0] = f2bf(a0[0]); o[1] = f2bf(a0[1]); o[2] = f2bf(a0[2]); o[3] = f2bf(a0[3]);
      int off = (r * 256 + ln * 8) ^ ((r & 7) << 4);
      *reinterpret_cast<ushort4v*>(reinterpret_cast<char*>(sA) + off) = o;
      idx = idxn; m = mn;
    }
  }
  __syncthreads();

  const int wave = tid >> 6;
  const int lane = tid & 63;
  const int wm = wave & 3, wn = wave >> 2;
  const int arow = wm * 16 + (lane & 15);
  const int kl = (lane >> 4) * 8;
  f32x4 acc[4];
  #pragma unroll
  for (int t = 0; t < 4; ++t) acc[t] = (f32x4){0.f, 0.f, 0.f, 0.f};

  // preload self-row A fragments (L2-local: same XCD slice), reused st=2,3
  short8 xa[4];
  {
    const int gr2 = row0 + arow;
    const bool av = gr2 < NN;
    #pragma unroll
    for (int ks = 0; ks < 4; ++ks)
      xa[ks] = av ? *reinterpret_cast<const short8*>(xb + (size_t)gr2 * DIM + ks * 32 + kl)
                  : (short8)0;
  }

  // 4 W-stages: {Wn,Ws} x {lo,hi 64 cols}; sW restaged between.
  #pragma unroll
  for (int st = 0; st < 4; ++st) {
    const bool self = st >= 2;
    const int  tbase = (st & 1) * 2;
    #pragma unroll
    for (int ks = 0; ks < 4; ++ks) {
      int k = ks * 32 + kl;
      short8 a;
      if (!self)
        a = *reinterpret_cast<const short8*>(
            reinterpret_cast<const char*>(sA) + ((arow * 256 + k * 2) ^ ((arow & 7) << 4)));
      else
        a = xa[ks];
      #pragma unroll
      for (int t = 0; t < 2; ++t) {
        int o = wn * 32 + t * 16 + (lane & 15);
        short8 bfr = *reinterpret_cast<const short8*>(
            reinterpret_cast<const char*>(sW) + ((o * 256 + k * 2) ^ ((o & 7) << 4)));
        acc[tbase + t] = __builtin_amdgcn_mfma_f32_16x16x32_bf16(a, bfr, acc[tbase + t], 0, 0, 0);
      }
    }
    if (st < 3) {
      __syncthreads();
      const unsigned short* wsrc = (st == 0) ? (wnb + 64 * DIM)
                                 : (st == 1) ? wsb : (wsb + 64 * DIM);
      int id = tid;
      #pragma unroll
      for (int it = 0; it < 2; ++it, id += 512) {
        int r = id >> 4, c = id & 15;
        short8 w = *reinterpret_cast<const short8*>(wsrc + r * DIM + c * 8);
        int off = (r * 256 + c * 16) ^ ((r & 7) << 4);
        *reinterpret_cast<short8*>(reinterpret_cast<char*>(sW) + off) = w;
      }
      __syncthreads();
    }
  }

  // epilogue: acc[t]: t<2 -> cols wn*32+(t&1)*16 (lo); t>=2 -> +64 (hi)
  #pragma unroll
  for (int t = 0; t < 4; ++t) {
    int col = ((t >> 1) ? 64 : 0) + wn * 32 + (t & 1) * 16 + (lane & 15);
    float bv = bsum[col];
    #pragma unroll
    for (int reg = 0; reg < 4; ++reg) {
      int gr = row0 + wm * 16 + (lane >> 4) * 4 + reg;
      if (gr < NN) out[(size_t)gr * DIM + col] = acc[t][reg] + bv;
    }
  }
}

extern "C" void kernel_launch(void* const* d_in, const int* in_sizes, int n_in,
                              void* d_out, int out_size, void* d_ws, size_t ws_size,
                              hipStream_t stream) {
  const float* x  = (const float*)d_in[0];
  const int*   ei = (const int*)d_in[1];
  const float* Wn = (const float*)d_in[2];
  const float* bn = (const float*)d_in[3];
  const float* Ws = (const float*)d_in[4];
  const float* bs = (const float*)d_in[5];
  float* out = (float*)d_out;
  char* ws = (char*)d_ws;

  unsigned short* wnb = (unsigned short*)(ws + 0);         // 32KB
  unsigned short* wsb = (unsigned short*)(ws + 32768);     // 32KB
  float* bsum        = (float*)(ws + 65536);               // 512B
  int* cnt           = (int*)(ws + 66560);                 // 400KB
  int* ovfcnt        = (int*)(ws + 466560);                // 32B (in memset range)
  int2* ovf          = (int2*)(ws + 466688);               // 128KB (8x2048x8B)
  int* slots         = (int*)(ws + 597760);                // 11.2MB
  unsigned short* xb = (unsigned short*)(ws + 11797760);   // 25.6MB (end 37.4MB)

  hipMemsetAsync(cnt, 0, 400064, stream);  // cnt + ovfcnt[8]
  prep_scatter_kernel<<<CVT_BLK + SC_BLK, 256, 0, stream>>>(
      x, ei, Wn, bn, Ws, bs, xb, wnb, wsb, bsum, cnt, ovfcnt, ovf, slots);
  fusedgemm_kernel<<<FGRID, 512, 0, stream>>>(
      xb, cnt, slots, ovf, ovfcnt, wnb, wsb, bsum, out);
}

// Round 17
// 170.827 us; speedup vs baseline: 1.0690x; 1.0690x over previous
//
#include <hip/hip_runtime.h>
#include <hip/hip_bf16.h>

#define NN 100000
#define NE 1600000
#define DIM 128
#define BM 64
#define CAP 28
#define OVFCAP 2048        // per slice
#define CVT_BLK 1024
#define SC_BLK 2048
#define SLICE 12544        // 196*64 nodes per XCD slice
#define FGRID 1568         // 8*196

typedef __attribute__((ext_vector_type(8))) short short8;
typedef __attribute__((ext_vector_type(4))) float f32x4;
typedef __attribute__((ext_vector_type(4))) unsigned short ushort4v;
typedef __attribute__((ext_vector_type(4))) int int4v;

__device__ __forceinline__ unsigned short f2bf(float f) {
  union { float f; unsigned u; } v; v.f = f;
  unsigned r = v.u + 0x7fffu + ((v.u >> 16) & 1u);
  return (unsigned short)(r >> 16);
}
__device__ __forceinline__ float bf2f(unsigned short h) {
  union { unsigned u; float f; } v; v.u = ((unsigned)h) << 16;
  return v.f;
}

// K1: XCD-sliced prep (R14 form: int4 dst scan, per-slice ovf lists).
__global__ __launch_bounds__(256) void prep_scatter_kernel(
    const float* __restrict__ x, const int* __restrict__ ei,
    const float* __restrict__ Wn, const float* __restrict__ bn,
    const float* __restrict__ Ws, const float* __restrict__ bs,
    unsigned short* __restrict__ xb, unsigned short* __restrict__ wnb,
    unsigned short* __restrict__ wsb, float* __restrict__ bsum,
    int* __restrict__ cnt, int* __restrict__ ovfcnt, int2* __restrict__ ovf,
    int* __restrict__ slots) {
  int b = blockIdx.x;
  if (b < CVT_BLK) {
    const int slice = b & 7;
    const int tid_g = (b >> 3) * 256 + threadIdx.x;
    const int r0 = slice * SLICE;
    const int r1 = min(r0 + SLICE, NN);
    const int i0 = r0 * (DIM / 4), i1 = r1 * (DIM / 4);
    for (int i = i0 + tid_g; i < i1; i += 128 * 256) {
      f32x4 v = reinterpret_cast<const f32x4*>(x)[i];
      ushort4v u;
      u[0] = f2bf(v[0]); u[1] = f2bf(v[1]); u[2] = f2bf(v[2]); u[3] = f2bf(v[3]);
      reinterpret_cast<ushort4v*>(xb)[i] = u;
    }
    if (slice == 0) {
      if (tid_g < DIM * DIM) { wnb[tid_g] = f2bf(Wn[tid_g]); wsb[tid_g] = f2bf(Ws[tid_g]); }
      if (tid_g < DIM) bsum[tid_g] = bn[tid_g] + bs[tid_g];
    }
  } else {
    const int sb  = b - CVT_BLK;              // 0..2047
    const int sl  = sb & 7;
    const int lo  = sl * SLICE;
    const int hi  = min(lo + SLICE, NN);
    const int rng = hi - lo;
    const int tid_g = (sb >> 3) * 256 + threadIdx.x;  // 0..65535
    const int STR = 256 * 256;
    const int NCH = NE / 4;                   // 400000 4-edge chunks
    for (int c = tid_g; c < NCH; c += STR) {
      int4v d4 = *reinterpret_cast<const int4v*>(ei + NE + 4 * c);
      #pragma unroll
      for (int j = 0; j < 4; ++j) {
        int d = d4[j];
        if ((unsigned)(d - lo) < (unsigned)rng) {
          int s = ei[4 * c + j];
          if ((unsigned)s >= NN) continue;
          int r = atomicAdd(&cnt[d], 1);
          if (r < CAP) {
            slots[d * CAP + r] = s;
          } else {
            int o = atomicAdd(&ovfcnt[sl], 1);
            if (o < OVFCAP) ovf[sl * OVFCAP + o] = make_int2(d, s);
          }
        }
      }
    }
  }
}

// K2: fused aggregate + dual MFMA GEMM (R13-proven 86us: half-width sW 16KB,
// sA+sX staged, LDS ~51KB -> 3 blocks/CU; acc persists across 4 W-stages).
__global__ __launch_bounds__(512) void fusedgemm_kernel(
    const unsigned short* __restrict__ xb,
    const int* __restrict__ cnt, const int* __restrict__ slots,
    const int2* __restrict__ ovf, const int* __restrict__ ovfcnt,
    const unsigned short* __restrict__ wnb, const unsigned short* __restrict__ wsb,
    const float* __restrict__ bsum, float* __restrict__ out) {
  __shared__ unsigned short sW[64 * DIM];   // 16KB
  __shared__ unsigned short sA[BM * DIM];   // 16KB
  __shared__ unsigned short sX[BM * DIM];   // 16KB
  __shared__ int2 lovf[256];                // 2KB
  __shared__ int lovfn;
  const int tid = threadIdx.x;
  const int slice = blockIdx.x & 7;
  const int row0 = slice * SLICE + (blockIdx.x >> 3) * BM;
  if (row0 >= NN) return;

  if (tid == 0) lovfn = 0;
  // stage sX (self features)
  #pragma unroll
  for (int it = 0; it < 2; ++it) {
    int id = it * 512 + tid;
    int r = id >> 4, c = id & 15;
    int gr = row0 + r;
    short8 v = (short8)0;
    if (gr < NN) v = *reinterpret_cast<const short8*>(xb + (size_t)gr * DIM + c * 8);
    int off = (r * 256 + c * 16) ^ ((r & 7) << 4);
    *reinterpret_cast<short8*>(reinterpret_cast<char*>(sX) + off) = v;
  }
  // stage sW = Wn rows 0-63
  {
    int id = tid;
    #pragma unroll
    for (int it = 0; it < 2; ++it, id += 512) {
      int r = id >> 4, c = id & 15;
      short8 w = *reinterpret_cast<const short8*>(wnb + r * DIM + c * 8);
      int off = (r * 256 + c * 16) ^ ((r & 7) << 4);
      *reinterpret_cast<short8*>(reinterpret_cast<char*>(sW) + off) = w;
    }
  }
  __syncthreads();   // lovfn init visible

  // pick this block's overflow pairs from ITS SLICE's list only
  {
    int ovfn = min(ovfcnt[slice], OVFCAP);
    const int2* osl = ovf + slice * OVFCAP;
    for (int k = tid; k < ovfn; k += 512) {
      int2 p = osl[k];
      if ((unsigned)(p.x - row0) < (unsigned)BM) {
        int t = atomicAdd(&lovfn, 1);
        if (t < 256) lovf[t] = p;
      }
    }
  }
  __syncthreads();

  // aggregate: 16 groups x 32 lanes; 4 nodes per group; idx prefetch 1 ahead
  {
    const int lg = tid >> 5, ln = tid & 31;
    int g = row0 + lg;
    int m = 0, idx = 0;
    if (g < NN) {
      m = min(cnt[g], CAP);
      if (ln < m) idx = slots[g * CAP + ln];
    }
    const int lcnt = min(lovfn, 256);
    for (int it = 0; it < 4; ++it) {
      int r = it * 16 + lg;
      int gcur = row0 + r;
      int mn = 0, idxn = 0;
      if (it < 3) {
        int gn = row0 + (it + 1) * 16 + lg;
        if (gn < NN) {
          mn = min(cnt[gn], CAP);
          if (ln < mn) idxn = slots[gn * CAP + ln];
        }
      }
      f32x4 a0 = (f32x4){0.f,0.f,0.f,0.f}, a1 = a0, a2 = a0, a3 = a0;
      f32x4 a4 = a0, a5 = a0, a6 = a0, a7 = a0;
      int e = 0;
      for (; e + 7 < m; e += 8) {
        int s0 = __shfl(idx, e, 32),     s1 = __shfl(idx, e + 1, 32);
        int s2 = __shfl(idx, e + 2, 32), s3 = __shfl(idx, e + 3, 32);
        int s4 = __shfl(idx, e + 4, 32), s5 = __shfl(idx, e + 5, 32);
        int s6 = __shfl(idx, e + 6, 32), s7 = __shfl(idx, e + 7, 32);
        ushort4v u0 = *reinterpret_cast<const ushort4v*>(xb + (size_t)s0 * DIM + ln * 4);
        ushort4v u1 = *reinterpret_cast<const ushort4v*>(xb + (size_t)s1 * DIM + ln * 4);
        ushort4v u2 = *reinterpret_cast<const ushort4v*>(xb + (size_t)s2 * DIM + ln * 4);
        ushort4v u3 = *reinterpret_cast<const ushort4v*>(xb + (size_t)s3 * DIM + ln * 4);
        ushort4v u4 = *reinterpret_cast<const ushort4v*>(xb + (size_t)s4 * DIM + ln * 4);
        ushort4v u5 = *reinterpret_cast<const ushort4v*>(xb + (size_t)s5 * DIM + ln * 4);
        ushort4v u6 = *reinterpret_cast<const ushort4v*>(xb + (size_t)s6 * DIM + ln * 4);
        ushort4v u7 = *reinterpret_cast<const ushort4v*>(xb + (size_t)s7 * DIM + ln * 4);
        #pragma unroll
        for (int j = 0; j < 4; ++j) {
          a0[j] += bf2f(u0[j]); a1[j] += bf2f(u1[j]);
          a2[j] += bf2f(u2[j]); a3[j] += bf2f(u3[j]);
          a4[j] += bf2f(u4[j]); a5[j] += bf2f(u5[j]);
          a6[j] += bf2f(u6[j]); a7[j] += bf2f(u7[j]);
        }
      }
      for (; e + 3 < m; e += 4) {
        int s0 = __shfl(idx, e, 32),     s1 = __shfl(idx, e + 1, 32);
        int s2 = __shfl(idx, e + 2, 32), s3 = __shfl(idx, e + 3, 32);
        ushort4v u0 = *reinterpret_cast<const ushort4v*>(xb + (size_t)s0 * DIM + ln * 4);
        ushort4v u1 = *reinterpret_cast<const ushort4v*>(xb + (size_t)s1 * DIM + ln * 4);
        ushort4v u2 = *reinterpret_cast<const ushort4v*>(xb + (size_t)s2 * DIM + ln * 4);
        ushort4v u3 = *reinterpret_cast<const ushort4v*>(xb + (size_t)s3 * DIM + ln * 4);
        #pragma unroll
        for (int j = 0; j < 4; ++j) {
          a0[j] += bf2f(u0[j]); a1[j] += bf2f(u1[j]);
          a2[j] += bf2f(u2[j]); a3[j] += bf2f(u3[j]);
        }
      }
      for (; e < m; ++e) {
        int s0 = __shfl(idx, e, 32);
        ushort4v u0 = *reinterpret_cast<const ushort4v*>(xb + (size_t)s0 * DIM + ln * 4);
        #pragma unroll
        for (int j = 0; j < 4; ++j) a0[j] += bf2f(u0[j]);
      }
      for (int k2 = 0; k2 < lcnt; ++k2) {
        int2 p = lovf[k2];
        if (p.x == gcur) {
          ushort4v u0 = *reinterpret_cast<const ushort4v*>(xb + (size_t)p.y * DIM + ln * 4);
          #pragma unroll
          for (int j = 0; j < 4; ++j) a0[j] += bf2f(u0[j]);
        }
      }
      a0 += a1; a2 += a3; a4 += a5; a6 += a7;
      a0 += a2; a4 += a6; a0 += a4;
      ushort4v o;
      o[0] = f2bf(a0[0]); o[1] = f2bf(a0[1]); o[2] = f2bf(a0[2]); o[3] = f2bf(a0[3]);
      int off = (r * 256 + ln * 8) ^ ((r & 7) << 4);
      *reinterpret_cast<ushort4v*>(reinterpret_cast<char*>(sA) + off) = o;
      idx = idxn; m = mn;
    }
  }
  __syncthreads();

  const int wave = tid >> 6;
  const int lane = tid & 63;
  const int wm = wave & 3, wn = wave >> 2;
  const int arow = wm * 16 + (lane & 15);
  const int kl = (lane >> 4) * 8;
  f32x4 acc[4];
  #pragma unroll
  for (int t = 0; t < 4; ++t) acc[t] = (f32x4){0.f, 0.f, 0.f, 0.f};

  // 4 W-stages: {Wn,Ws} x {lo,hi 64 cols}; sW restaged between.
  #pragma unroll
  for (int st = 0; st < 4; ++st) {
    const bool self = st >= 2;
    const int  tbase = (st & 1) * 2;
    #pragma unroll
    for (int ks = 0; ks < 4; ++ks) {
      int k = ks * 32 + kl;
      short8 a;
      if (!self)
        a = *reinterpret_cast<const short8*>(
            reinterpret_cast<const char*>(sA) + ((arow * 256 + k * 2) ^ ((arow & 7) << 4)));
      else
        a = *reinterpret_cast<const short8*>(
            reinterpret_cast<const char*>(sX) + ((arow * 256 + k * 2) ^ ((arow & 7) << 4)));
      #pragma unroll
      for (int t = 0; t < 2; ++t) {
        int o = wn * 32 + t * 16 + (lane & 15);
        short8 bfr = *reinterpret_cast<const short8*>(
            reinterpret_cast<const char*>(sW) + ((o * 256 + k * 2) ^ ((o & 7) << 4)));
        acc[tbase + t] = __builtin_amdgcn_mfma_f32_16x16x32_bf16(a, bfr, acc[tbase + t], 0, 0, 0);
      }
    }
    if (st < 3) {
      __syncthreads();
      const unsigned short* wsrc = (st == 0) ? (wnb + 64 * DIM)
                                 : (st == 1) ? wsb : (wsb + 64 * DIM);
      int id = tid;
      #pragma unroll
      for (int it = 0; it < 2; ++it, id += 512) {
        int r = id >> 4, c = id & 15;
        short8 w = *reinterpret_cast<const short8*>(wsrc + r * DIM + c * 8);
        int off = (r * 256 + c * 16) ^ ((r & 7) << 4);
        *reinterpret_cast<short8*>(reinterpret_cast<char*>(sW) + off) = w;
      }
      __syncthreads();
    }
  }

  // epilogue: acc[t]: t<2 -> cols wn*32+(t&1)*16 (lo); t>=2 -> +64 (hi)
  #pragma unroll
  for (int t = 0; t < 4; ++t) {
    int col = ((t >> 1) ? 64 : 0) + wn * 32 + (t & 1) * 16 + (lane & 15);
    float bv = bsum[col];
    #pragma unroll
    for (int reg = 0; reg < 4; ++reg) {
      int gr = row0 + wm * 16 + (lane >> 4) * 4 + reg;
      if (gr < NN) out[(size_t)gr * DIM + col] = acc[t][reg] + bv;
    }
  }
}

extern "C" void kernel_launch(void* const* d_in, const int* in_sizes, int n_in,
                              void* d_out, int out_size, void* d_ws, size_t ws_size,
                              hipStream_t stream) {
  const float* x  = (const float*)d_in[0];
  const int*   ei = (const int*)d_in[1];
  const float* Wn = (const float*)d_in[2];
  const float* bn = (const float*)d_in[3];
  const float* Ws = (const float*)d_in[4];
  const float* bs = (const float*)d_in[5];
  float* out = (float*)d_out;
  char* ws = (char*)d_ws;

  unsigned short* wnb = (unsigned short*)(ws + 0);         // 32KB
  unsigned short* wsb = (unsigned short*)(ws + 32768);     // 32KB
  float* bsum        = (float*)(ws + 65536);               // 512B
  int* cnt           = (int*)(ws + 66560);                 // 400KB
  int* ovfcnt        = (int*)(ws + 466560);                // 32B (in memset range)
  int2* ovf          = (int2*)(ws + 466688);               // 128KB (8x2048x8B)
  int* slots         = (int*)(ws + 597760);                // 11.2MB
  unsigned short* xb = (unsigned short*)(ws + 11797760);   // 25.6MB (end 37.4MB)

  hipMemsetAsync(cnt, 0, 400064, stream);  // cnt + ovfcnt[8]
  prep_scatter_kernel<<<CVT_BLK + SC_BLK, 256, 0, stream>>>(
      x, ei, Wn, bn, Ws, bs, xb, wnb, wsb, bsum, cnt, ovfcnt, ovf, slots);
  fusedgemm_kernel<<<FGRID, 512, 0, stream>>>(
      xb, cnt, slots, ovf, ovfcnt, wnb, wsb, bsum, out);
}